// Round 11
// baseline (27645.279 us; speedup 1.0000x reference)
//
#include <hip/hip_runtime.h>
#include <hip/hip_bf16.h>
#include <hip/hip_fp16.h>
#include <math.h>

// Problem sizes
#define BB 256
#define TT 64
#define HH 512
#define SS 256
#define KKC 1024

// ws float offsets — total 1,837,056 floats = 7.35 MB
#define OFF_XT 0
#define OFF_XE (OFF_XT + BB*4)
#define OFF_XS (OFF_XE + BB*HH)
#define OFF_HA (OFF_XS + BB*HH)
#define OFF_HB (OFF_HA + BB*HH)
#define OFF_C  (OFF_HB + BB*HH)
#define OFF_XO (OFF_C  + BB*HH)
#define OFF_LOG (OFF_XO + BB*HH)
#define OFF_IDX (OFF_LOG + BB*4*KKC)

// mask decode (robust to int32/int64/f32/f64/bf16/fp16 encodings; fallback 32)
__device__ __forceinline__ int decode_mask(const int* p) {
  if (p == nullptr) return 32;
  unsigned w0 = (unsigned)p[0];
  if (w0 >= 1u && w0 <= 63u) return (int)w0;
  { float f = __uint_as_float(w0);
    if (f >= 1.f && f <= 63.f && f == floorf(f)) return (int)f; }
  if (w0 == 0u) {
    double dv = __hiloint2double(p[1], 0);
    if (dv >= 1.0 && dv <= 63.0 && dv == floor(dv)) return (int)dv;
    return 32;
  }
  if (w0 <= 0xFFFFu) {
    float fb = __uint_as_float(w0 << 16);
    if (fb >= 1.f && fb <= 63.f && fb == floorf(fb)) return (int)fb;
    __half_raw hr; hr.x = (unsigned short)w0;
    float fh = __half2float(__half(hr));
    if (fh >= 1.f && fh <= 63.f && fh == floorf(fh)) return (int)fh;
  }
  return 32;
}

// ---------------- init: h,c and output edges (f32 out!) ----------------
__global__ __launch_bounds__(256) void k_init(
    const float* __restrict__ obs, const float* __restrict__ h0,
    const float* __restrict__ c0, float* __restrict__ ws,
    float* __restrict__ out)
{
  int i = blockIdx.x*256 + threadIdx.x;   // 512 blocks -> BB*HH
  ws[OFF_HA + i] = h0[i];
  ws[OFF_C  + i] = c0[i];
  if (i < BB*4) {
    int b = i >> 2, d = i & 3;
    out[(b*TT + 0)*4 + d]  = obs[(b*TT + 0)*4 + d];
    out[(b*TT + 63)*4 + d] = obs[(b*TT + 63)*4 + d];
  }
}

// ---------------- sampling: build x_t (and write sampled_delta) ----------------
__global__ __launch_bounds__(256) void k_sample(
    const float* __restrict__ obs, const float* __restrict__ cx,
    const float* __restrict__ cy, const float* __restrict__ cw,
    const float* __restrict__ ch, const int* maskp,
    float* __restrict__ ws, float* __restrict__ out, int t)
{
  int i = blockIdx.x*256 + threadIdx.x;   // 4 blocks -> B*4
  int b = i >> 2, d = i & 3;
  int mi = decode_mask(maskp);
  float v;
  if (t == 0 || t < mi) {
    v = obs[(b*TT + t)*4 + d];
  } else {
    int idx = ((const int*)(ws + OFF_IDX))[i];
    idx &= (KKC - 1);
    const float* cen = d==0 ? cx : (d==1 ? cy : (d==2 ? cw : ch));
    v = cen[idx];
  }
  ws[OFF_XT + i] = v;
  if (t >= 1) out[(b*TT + t)*4 + d] = v;
}

// ---------------- residual block: x_t -> xe ----------------
__global__ __launch_bounds__(512) void k_xe(
    const float* __restrict__ W_rb1, const float* __restrict__ b_rb1,
    const float* __restrict__ W_rb2, const float* __restrict__ b_rb2,
    const float* __restrict__ W_rbs, const float* __restrict__ b_rbs,
    float* __restrict__ ws)
{
  int b0 = blockIdx.x*4, tid = threadIdx.x;
  __shared__ float x4[4][4];
  __shared__ float xr[4][HH];
  if (tid < 16) x4[tid>>2][tid&3] = ws[OFF_XT + b0*4 + tid];
  __syncthreads();
  float w0 = W_rb1[tid*4+0], w1 = W_rb1[tid*4+1], w2 = W_rb1[tid*4+2], w3 = W_rb1[tid*4+3];
  float b1 = b_rb1[tid];
  #pragma unroll
  for (int r = 0; r < 4; r++) {
    float a = b1 + x4[r][0]*w0 + x4[r][1]*w1 + x4[r][2]*w2 + x4[r][3]*w3;
    xr[r][tid] = fmaxf(a, 0.f);
  }
  __syncthreads();
  float s0 = W_rbs[tid*4+0], s1 = W_rbs[tid*4+1], s2 = W_rbs[tid*4+2], s3 = W_rbs[tid*4+3];
  double bias = (double)b_rb2[tid] + (double)b_rbs[tid];
  double acc[4];
  #pragma unroll
  for (int r = 0; r < 4; r++)
    acc[r] = bias + (double)(x4[r][0]*s0) + (double)(x4[r][1]*s1)
                  + (double)(x4[r][2]*s2) + (double)(x4[r][3]*s3);
  const float* w2p = W_rb2 + (size_t)tid*HH;
  for (int k = 0; k < HH; k++) {
    double w = w2p[k];
    #pragma unroll
    for (int r = 0; r < 4; r++) acc[r] += (double)xr[r][k] * w;
  }
  #pragma unroll
  for (int r = 0; r < 4; r++)
    ws[OFF_XE + (b0+r)*HH + tid] = fmaxf((float)acc[r], 0.f);
}

// ---------------- embedding: [xe | social_t] -> xs ----------------
__global__ __launch_bounds__(512) void k_xs(
    const float* __restrict__ social, const float* __restrict__ W_emb,
    const float* __restrict__ b_emb, float* __restrict__ ws, int t)
{
  int b0 = blockIdx.x*4, tid = threadIdx.x;
  __shared__ float av[4][768];
  for (int p = tid; p < 4*768; p += 512) {
    int r = p / 768, kk = p - r*768;
    av[r][kk] = (kk < HH) ? ws[OFF_XE + (b0+r)*HH + kk]
                          : social[((size_t)(b0+r)*TT + t)*SS + (kk - HH)];
  }
  __syncthreads();
  double acc[4];
  double be = b_emb[tid];
  #pragma unroll
  for (int r = 0; r < 4; r++) acc[r] = be;
  const float* wp = W_emb + (size_t)tid*768;
  for (int k = 0; k < 768; k++) {
    double w = wp[k];
    #pragma unroll
    for (int r = 0; r < 4; r++) acc[r] += (double)av[r][k] * w;
  }
  #pragma unroll
  for (int r = 0; r < 4; r++)
    ws[OFF_XS + (b0+r)*HH + tid] = fmaxf((float)acc[r], 0.f);
}

// ---------------- LSTM gates + cell update ----------------
__global__ __launch_bounds__(512) void k_gates(
    const float* __restrict__ W_ih, const float* __restrict__ b_ih,
    const float* __restrict__ W_hh, const float* __restrict__ b_hh,
    float* __restrict__ ws, const float* __restrict__ h_cur,
    float* __restrict__ h_nxt)
{
  int b0 = blockIdx.x*4, tid = threadIdx.x;   // tid = h-unit j
  __shared__ float av[4][1024];
  for (int p = tid; p < 4096; p += 512) {
    int r = p >> 10, kk = p & 1023;
    av[r][kk] = (kk < HH) ? ws[OFF_XS + (b0+r)*HH + kk]
                          : h_cur[(b0+r)*HH + (kk - HH)];
  }
  __syncthreads();
  double g[4][4];
  for (int gi = 0; gi < 4; gi++) {
    int row = gi*HH + tid;
    double bsum = (double)b_ih[row] + (double)b_hh[row];
    double a[4];
    #pragma unroll
    for (int r = 0; r < 4; r++) a[r] = bsum;
    const float* wi = W_ih + (size_t)row*HH;
    const float* wh = W_hh + (size_t)row*HH;
    for (int k = 0; k < HH; k++) {
      double w = wi[k];
      #pragma unroll
      for (int r = 0; r < 4; r++) a[r] += (double)av[r][k] * w;
    }
    for (int k = 0; k < HH; k++) {
      double w = wh[k];
      #pragma unroll
      for (int r = 0; r < 4; r++) a[r] += (double)av[r][HH + k] * w;
    }
    #pragma unroll
    for (int r = 0; r < 4; r++) g[gi][r] = a[r];
  }
  #pragma unroll
  for (int r = 0; r < 4; r++) {
    int b = b0 + r;
    float co = ws[OFF_C + b*HH + tid];
    double si = 1.0/(1.0 + exp(-g[0][r]));
    double sf = 1.0/(1.0 + exp(-g[1][r]));
    double tg = tanh(g[2][r]);
    double so = 1.0/(1.0 + exp(-g[3][r]));
    float c2 = (float)(sf*(double)co + si*tg);
    float h2 = (float)(so*tanh((double)c2));
    ws[OFF_C + b*HH + tid] = c2;
    h_nxt[b*HH + tid] = h2;
    ws[OFF_XO + b*HH + tid] = h2 + ws[OFF_XE + b*HH + tid];
  }
}

// ---------------- cluster heads: xo -> logits (f32 to ws AND f32 out) ----------------
__global__ __launch_bounds__(512) void k_heads(
    const float* __restrict__ W_fx, const float* __restrict__ b_fx,
    const float* __restrict__ W_fy, const float* __restrict__ b_fy,
    const float* __restrict__ W_fw, const float* __restrict__ b_fw,
    const float* __restrict__ W_fh, const float* __restrict__ b_fh,
    float* __restrict__ ws, float* __restrict__ out, int t)
{
  int bg = blockIdx.x >> 2, hd = blockIdx.x & 3;
  int b0 = bg*4, tid = threadIdx.x;
  __shared__ float av[4][HH];
  for (int p = tid; p < 4*HH; p += 512) {
    int r = p >> 9, kk = p & 511;
    av[r][kk] = ws[OFF_XO + (b0+r)*HH + kk];
  }
  __syncthreads();
  const float* Wf = hd==0 ? W_fx : (hd==1 ? W_fy : (hd==2 ? W_fw : W_fh));
  const float* bf = hd==0 ? b_fx : (hd==1 ? b_fy : (hd==2 ? b_fw : b_fh));
  for (int cc = 0; cc < 2; cc++) {
    int c = tid + cc*512;
    double a[4];
    double bv = bf[c];
    #pragma unroll
    for (int r = 0; r < 4; r++) a[r] = bv;
    const float* wp = Wf + (size_t)c*HH;
    for (int k = 0; k < HH; k++) {
      double w = wp[k];
      #pragma unroll
      for (int r = 0; r < 4; r++) a[r] += (double)av[r][k] * w;
    }
    #pragma unroll
    for (int r = 0; r < 4; r++) {
      float lv = (float)a[r];
      ws[OFF_LOG + ((size_t)((b0+r)*4 + hd))*KKC + c] = lv;
      out[(size_t)BB*TT*4 + ((size_t)hd*BB + (b0+r))*63*KKC + (size_t)t*KKC + c] = lv;
    }
  }
}

// ---------------- argmax (np semantics) ----------------
__global__ __launch_bounds__(256) void k_argmax(float* __restrict__ ws)
{
  int slot = blockIdx.x, tid = threadIdx.x;
  const float* L = ws + OFF_LOG + (size_t)slot*KKC;
  float best = -1e38f; int bi_ = 0x7FFFFFFF;
  for (int k = tid; k < KKC; k += 256) {
    float v = L[k];
    if (v > best || (v == best && k < bi_)) { best = v; bi_ = k; }
  }
  __shared__ float sv[256];
  __shared__ int si_[256];
  sv[tid] = best; si_[tid] = bi_;
  __syncthreads();
  for (int s = 128; s > 0; s >>= 1) {
    if (tid < s) {
      float v2 = sv[tid+s]; int i2 = si_[tid+s];
      if (v2 > sv[tid] || (v2 == sv[tid] && i2 < si_[tid])) { sv[tid] = v2; si_[tid] = i2; }
    }
    __syncthreads();
  }
  if (tid == 0) ((int*)(ws + OFF_IDX))[slot] = si_[0];
}

extern "C" void kernel_launch(void* const* d_in, const int* in_sizes, int n_in,
                              void* d_out, int out_size, void* d_ws, size_t ws_size,
                              hipStream_t stream)
{
  const float* obs    = (const float*)d_in[0];
  const float* social = (const float*)d_in[1];
  const int*   maskp  = (const int*)d_in[2];
  const float* cx = (const float*)d_in[3];
  const float* cy = (const float*)d_in[4];
  const float* cw = (const float*)d_in[5];
  const float* ch = (const float*)d_in[6];
  const float* W_rb1 = (const float*)d_in[7];
  const float* b_rb1 = (const float*)d_in[8];
  const float* W_rb2 = (const float*)d_in[9];
  const float* b_rb2 = (const float*)d_in[10];
  const float* W_rbs = (const float*)d_in[11];
  const float* b_rbs = (const float*)d_in[12];
  const float* W_emb = (const float*)d_in[13];
  const float* b_emb = (const float*)d_in[14];
  const float* W_ih  = (const float*)d_in[15];
  const float* b_ih  = (const float*)d_in[16];
  const float* W_hh  = (const float*)d_in[17];
  const float* b_hh  = (const float*)d_in[18];
  const float* W_fx  = (const float*)d_in[19];
  const float* b_fx  = (const float*)d_in[20];
  const float* W_fy  = (const float*)d_in[21];
  const float* b_fy  = (const float*)d_in[22];
  const float* W_fw  = (const float*)d_in[23];
  const float* b_fw  = (const float*)d_in[24];
  const float* W_fh  = (const float*)d_in[25];
  const float* b_fh  = (const float*)d_in[26];
  const float* h0 = (const float*)d_in[27];
  const float* c0 = (const float*)d_in[28];
  float* ws = (float*)d_ws;
  float* out = (float*)d_out;   // <<< reference output dtype is float32

  hipLaunchKernelGGL(k_init, dim3(512), dim3(256), 0, stream, obs, h0, c0, ws, out);

  for (int t = 0; t < 63; t++) {
    const float* h_cur = ws + ((t & 1) ? OFF_HB : OFF_HA);
    float*       h_nxt = ws + ((t & 1) ? OFF_HA : OFF_HB);
    hipLaunchKernelGGL(k_sample, dim3(4), dim3(256), 0, stream,
                       obs, cx, cy, cw, ch, maskp, ws, out, t);
    hipLaunchKernelGGL(k_xe, dim3(64), dim3(512), 0, stream,
                       W_rb1, b_rb1, W_rb2, b_rb2, W_rbs, b_rbs, ws);
    hipLaunchKernelGGL(k_xs, dim3(64), dim3(512), 0, stream, social, W_emb, b_emb, ws, t);
    hipLaunchKernelGGL(k_gates, dim3(64), dim3(512), 0, stream,
                       W_ih, b_ih, W_hh, b_hh, ws, h_cur, h_nxt);
    hipLaunchKernelGGL(k_heads, dim3(256), dim3(512), 0, stream,
                       W_fx, b_fx, W_fy, b_fy, W_fw, b_fw, W_fh, b_fh, ws, out, t);
    hipLaunchKernelGGL(k_argmax, dim3(1024), dim3(256), 0, stream, ws);
  }
}

// Round 12
// 10089.713 us; speedup vs baseline: 2.7399x; 2.7399x over previous
//
#include <hip/hip_runtime.h>
#include <hip/hip_bf16.h>
#include <hip/hip_fp16.h>
#include <math.h>

// Problem sizes
#define BB 256
#define TT 64
#define HH 512
#define SS 256
#define KKC 1024

// ws float offsets — 788,480 floats = 3.15 MB
#define OFF_XE 0
#define OFF_XS (OFF_XE + BB*HH)
#define OFF_HA (OFF_XS + BB*HH)
#define OFF_HB (OFF_HA + BB*HH)
#define OFF_C  (OFF_HB + BB*HH)
#define OFF_XO (OFF_C  + BB*HH)
#define OFF_SLOT (OFF_XO + BB*HH)   // 1024 u64 argmax slots

__device__ __forceinline__ unsigned encf(float f) {
  unsigned u = __float_as_uint(f);
  return (u & 0x80000000u) ? ~u : (u | 0x80000000u);
}

__device__ __forceinline__ unsigned long long shfl_xor_u64(unsigned long long v, int m) {
  unsigned lo = (unsigned)v, hi = (unsigned)(v >> 32);
  lo = __shfl_xor(lo, m, 64);
  hi = __shfl_xor(hi, m, 64);
  return ((unsigned long long)hi << 32) | lo;
}

// mask decode (robust; proven on this dataset in round 11)
__device__ __forceinline__ int decode_mask(const int* p) {
  if (p == nullptr) return 32;
  unsigned w0 = (unsigned)p[0];
  if (w0 >= 1u && w0 <= 63u) return (int)w0;
  { float f = __uint_as_float(w0);
    if (f >= 1.f && f <= 63.f && f == floorf(f)) return (int)f; }
  if (w0 == 0u) {
    double dv = __hiloint2double(p[1], 0);
    if (dv >= 1.0 && dv <= 63.0 && dv == floor(dv)) return (int)dv;
    return 32;
  }
  if (w0 <= 0xFFFFu) {
    float fb = __uint_as_float(w0 << 16);
    if (fb >= 1.f && fb <= 63.f && fb == floorf(fb)) return (int)fb;
    __half_raw hr; hr.x = (unsigned short)w0;
    float fh = __half2float(__half(hr));
    if (fh >= 1.f && fh <= 63.f && fh == floorf(fh)) return (int)fh;
  }
  return 32;
}

// ---------------- init: h,c and output edges ----------------
__global__ __launch_bounds__(256) void k_init(
    const float* __restrict__ obs, const float* __restrict__ h0,
    const float* __restrict__ c0, float* __restrict__ ws,
    float* __restrict__ out)
{
  int i = blockIdx.x*256 + threadIdx.x;   // 512 blocks -> BB*HH
  ws[OFF_HA + i] = h0[i];
  ws[OFF_C  + i] = c0[i];
  if (i < BB*4) {
    int b = i >> 2, d = i & 3;
    out[(b*TT + 0)*4 + d]  = obs[(b*TT + 0)*4 + d];
    out[(b*TT + 63)*4 + d] = obs[(b*TT + 63)*4 + d];
  }
}

// ---------------- phase 1: sample (fused) + residual block -> xe ----------------
// grid 256 = 16 rowg x 16 colg ; tile 16 rows x 32 cols, k=512 in 8 tiles of 64
__global__ __launch_bounds__(256) void k_xe(
    const float* __restrict__ obs, const float* __restrict__ cx, const float* __restrict__ cy,
    const float* __restrict__ cw, const float* __restrict__ ch, const int* maskp,
    const float* __restrict__ W_rb1, const float* __restrict__ b_rb1,
    const float* __restrict__ W_rb2, const float* __restrict__ b_rb2,
    const float* __restrict__ W_rbs, const float* __restrict__ b_rbs,
    float* __restrict__ ws, float* __restrict__ out, int t)
{
  int bid = blockIdx.x, tid = threadIdx.x;
  int rowg = bid >> 4, colg = bid & 15;
  int r0 = rowg*16, c0 = colg*32;
  __shared__ float x_sm[16][4];
  __shared__ float xr_smT[HH][16];   // 32 KB, transposed fc1 output
  __shared__ float w_sm[64][36];
  if (tid < 64) {
    int r = tid >> 2, hd = tid & 3, b = r0 + r;
    int mi = decode_mask(maskp);
    float v;
    if (t == 0 || t < mi) {
      v = obs[(b*TT + t)*4 + hd];
    } else {
      const unsigned long long* slots = (const unsigned long long*)(ws + OFF_SLOT);
      unsigned long long s = slots[b*4 + hd];
      unsigned int kidx = 0xFFFFFFFFu - (unsigned int)(s & 0xFFFFFFFFull);
      const float* cen = hd==0 ? cx : (hd==1 ? cy : (hd==2 ? cw : ch));
      v = cen[kidx & (KKC-1)];
    }
    x_sm[r][hd] = v;
    if (t >= 1 && colg == 0) out[(b*TT + t)*4 + hd] = v;
  }
  __syncthreads();
  // fc1 + relu (recomputed per block; tiny: 16x512 from 4 inputs)
  for (int p = tid; p < 16*HH; p += 256) {
    int r = p & 15, j = p >> 4;
    float4 w = *(const float4*)&W_rb1[j*4];
    float a = b_rb1[j] + x_sm[r][0]*w.x + x_sm[r][1]*w.y + x_sm[r][2]*w.z + x_sm[r][3]*w.w;
    xr_smT[j][r] = fmaxf(a, 0.f);
  }
  int c = tid & 31, rg = tid >> 5;   // 32 cols x 8 row-pairs
  int col = c0 + c, ra = rg*2, rb = ra + 1;
  float4 wsd = *(const float4*)&W_rbs[col*4];
  double bias = (double)b_rb2[col] + (double)b_rbs[col];
  double acc0 = bias + (double)x_sm[ra][0]*wsd.x + (double)x_sm[ra][1]*wsd.y
                     + (double)x_sm[ra][2]*wsd.z + (double)x_sm[ra][3]*wsd.w;
  double acc1 = bias + (double)x_sm[rb][0]*wsd.x + (double)x_sm[rb][1]*wsd.y
                     + (double)x_sm[rb][2]*wsd.z + (double)x_sm[rb][3]*wsd.w;
  for (int kt = 0; kt < 8; kt++) {
    __syncthreads();   // first iter: xr_smT complete; later: prev compute done
    for (int p = 0; p < 2; p++) {
      int idx = tid + p*256;
      int wc = idx >> 4, kq = idx & 15;
      float4 v = *(const float4*)&W_rb2[(c0+wc)*HH + kt*64 + kq*4];
      w_sm[kq*4+0][wc] = v.x; w_sm[kq*4+1][wc] = v.y;
      w_sm[kq*4+2][wc] = v.z; w_sm[kq*4+3][wc] = v.w;
    }
    __syncthreads();
    #pragma unroll 4
    for (int kk = 0; kk < 64; kk++) {
      double w = (double)w_sm[kk][c];
      float2 a = *(const float2*)&xr_smT[kt*64+kk][ra];
      acc0 += (double)a.x * w;
      acc1 += (double)a.y * w;
    }
  }
  float* xe = ws + OFF_XE;
  xe[(r0+ra)*HH + col] = fmaxf((float)acc0, 0.f);
  xe[(r0+rb)*HH + col] = fmaxf((float)acc1, 0.f);
}

// ---------------- phase 2: embedding -> xs ----------------
// grid 256 = 16 rowg x 16 colg ; tile 16 x 32, k=768 in 12 tiles of 64
__global__ __launch_bounds__(256) void k_xs(
    const float* __restrict__ social, const float* __restrict__ W_emb,
    const float* __restrict__ b_emb, float* __restrict__ ws, int t)
{
  int bid = blockIdx.x, tid = threadIdx.x;
  int rowg = bid >> 4, colg = bid & 15;
  int r0 = rowg*16, c0 = colg*32;
  __shared__ float A_smT[64][20];
  __shared__ float w_sm[64][36];
  int c = tid & 31, rg = tid >> 5;
  int col = c0 + c, ra = rg*2, rb = ra + 1;
  double acc0 = (double)b_emb[col], acc1 = acc0;
  const float* XE = ws + OFF_XE;
  for (int kt = 0; kt < 12; kt++) {
    int k0 = kt*64;
    __syncthreads();
    { // stage A tile (transposed): 64k x 16r
      int r = tid & 15, q = tid >> 4;
      const float* src = (kt < 8) ? &XE[(r0+r)*HH + k0 + q*4]
                                  : &social[((size_t)(r0+r)*TT + t)*SS + (k0 - HH) + q*4];
      float4 v = *(const float4*)src;
      A_smT[q*4+0][r] = v.x; A_smT[q*4+1][r] = v.y;
      A_smT[q*4+2][r] = v.z; A_smT[q*4+3][r] = v.w;
    }
    for (int p = 0; p < 2; p++) {  // stage W tile (transposed): 64k x 32col
      int idx = tid + p*256;
      int wc = idx >> 4, kq = idx & 15;
      float4 v = *(const float4*)&W_emb[(c0+wc)*768 + k0 + kq*4];
      w_sm[kq*4+0][wc] = v.x; w_sm[kq*4+1][wc] = v.y;
      w_sm[kq*4+2][wc] = v.z; w_sm[kq*4+3][wc] = v.w;
    }
    __syncthreads();
    #pragma unroll 4
    for (int kk = 0; kk < 64; kk++) {
      double w = (double)w_sm[kk][c];
      float2 a = *(const float2*)&A_smT[kk][ra];
      acc0 += (double)a.x * w;
      acc1 += (double)a.y * w;
    }
  }
  float* XS = ws + OFF_XS;
  XS[(r0+ra)*HH + col] = fmaxf((float)acc0, 0.f);
  XS[(r0+rb)*HH + col] = fmaxf((float)acc1, 0.f);
}

// ---------------- phase 3: LSTM gates + cell update ----------------
// grid 256 = 16 rowg x 16 colg ; 512 threads; tile 16 rows x 128 gate-cols, k=1024
// local col l = jl*4 + g  <->  weight row = g*512 + colg*32 + jl
__global__ __launch_bounds__(512) void k_gates(
    const float* __restrict__ W_ih, const float* __restrict__ b_ih,
    const float* __restrict__ W_hh, const float* __restrict__ b_hh,
    float* __restrict__ ws, const float* __restrict__ h_cur,
    float* __restrict__ h_nxt)
{
  int bid = blockIdx.x, tid = threadIdx.x;
  int rowg = bid >> 4, colg = bid & 15;
  int r0 = rowg*16;
  int tx = tid & 63, ty = tid >> 6;   // ty in 0..7 -> rows ty*2, ty*2+1
  __shared__ float A_smT[64][20];
  __shared__ float w_sm[64][132];
  __shared__ float gt[16][132];
  const float* XS = ws + OFF_XS;
  int l0 = tx*2, l1 = l0 + 1;
  int row0 = (l0 & 3)*HH + colg*32 + (l0 >> 2);
  int row1 = (l1 & 3)*HH + colg*32 + (l1 >> 2);
  double bi0 = (double)b_ih[row0] + (double)b_hh[row0];
  double bi1 = (double)b_ih[row1] + (double)b_hh[row1];
  double acc[2][2];
  acc[0][0] = bi0; acc[0][1] = bi1; acc[1][0] = bi0; acc[1][1] = bi1;
  for (int kt = 0; kt < 16; kt++) {
    int k0 = kt*64;
    __syncthreads();
    if (tid < 256) { // stage A: 64k x 16r
      int r = tid & 15, q = tid >> 4;
      const float* src = (kt < 8) ? &XS[(r0+r)*HH + k0 + q*4]
                                  : &h_cur[(r0+r)*HH + (k0 - HH) + q*4];
      float4 v = *(const float4*)src;
      A_smT[q*4+0][r] = v.x; A_smT[q*4+1][r] = v.y;
      A_smT[q*4+2][r] = v.z; A_smT[q*4+3][r] = v.w;
    }
    for (int p = 0; p < 4; p++) {  // stage W: 64k x 128col
      int idx = tid + p*512;
      int wc = idx >> 4, kq = idx & 15;
      int wr = (wc & 3)*HH + colg*32 + (wc >> 2);
      const float* wsrc = (kt < 8) ? &W_ih[wr*HH + k0 + kq*4]
                                   : &W_hh[wr*HH + (k0 - HH) + kq*4];
      float4 v = *(const float4*)wsrc;
      w_sm[kq*4+0][wc] = v.x; w_sm[kq*4+1][wc] = v.y;
      w_sm[kq*4+2][wc] = v.z; w_sm[kq*4+3][wc] = v.w;
    }
    __syncthreads();
    #pragma unroll 4
    for (int kk = 0; kk < 64; kk++) {
      float2 w = *(const float2*)&w_sm[kk][tx*2];
      float2 a = *(const float2*)&A_smT[kk][ty*2];
      acc[0][0] += (double)a.x * (double)w.x; acc[0][1] += (double)a.x * (double)w.y;
      acc[1][0] += (double)a.y * (double)w.x; acc[1][1] += (double)a.y * (double)w.y;
    }
  }
  __syncthreads();
  #pragma unroll
  for (int i = 0; i < 2; i++) {
    gt[ty*2 + i][tx*2 + 0] = (float)acc[i][0];
    gt[ty*2 + i][tx*2 + 1] = (float)acc[i][1];
  }
  __syncthreads();
  float* C = ws + OFF_C;
  const float* XEb = ws + OFF_XE;
  float* XO = ws + OFF_XO;
  {
    int p = tid;   // 512 threads -> exactly 16 rows x 32 h-units
    int r = p >> 5, jl = p & 31;
    float4 g4 = *(const float4*)&gt[r][jl*4];   // i,f,g,o
    int b = r0 + r, jglob = colg*32 + jl;
    float co = C[b*HH + jglob];
    double si = 1.0/(1.0 + exp(-(double)g4.x));
    double sf = 1.0/(1.0 + exp(-(double)g4.y));
    double tg = tanh((double)g4.z);
    double so = 1.0/(1.0 + exp(-(double)g4.w));
    float c2 = (float)(sf*(double)co + si*tg);
    float h2 = (float)(so*tanh((double)c2));
    C[b*HH + jglob] = c2;
    h_nxt[b*HH + jglob] = h2;
    XO[b*HH + jglob] = h2 + XEb[b*HH + jglob];
  }
  // zero argmax slots (after k_xe consumed last step's, before k_heads refills)
  if (bid == 0) {
    unsigned long long* slots = (unsigned long long*)(ws + OFF_SLOT);
    for (int p = tid; p < BB*4; p += 512) slots[p] = 0ull;
  }
}

// ---------------- phase 4: cluster heads (f32) + fused argmax ----------------
// grid 512 = 16 rowg x 32 colg ; tile 16 rows x 128 head-cols, k=512
__global__ __launch_bounds__(256) void k_heads(
    const float* __restrict__ W_fx, const float* __restrict__ b_fx,
    const float* __restrict__ W_fy, const float* __restrict__ b_fy,
    const float* __restrict__ W_fw, const float* __restrict__ b_fw,
    const float* __restrict__ W_fh, const float* __restrict__ b_fh,
    float* __restrict__ ws, float* __restrict__ out, int t)
{
  int bid = blockIdx.x, tid = threadIdx.x;
  int rowg = bid >> 5, colg = bid & 31;
  int r0 = rowg*16;
  int hd = colg >> 3;
  int kbase = (colg & 7)*128;
  int tx = tid & 63, ty = tid >> 6;
  __shared__ float A_smT[64][20];
  __shared__ float w_sm[64][132];
  const float* Wf = hd==0 ? W_fx : (hd==1 ? W_fy : (hd==2 ? W_fw : W_fh));
  const float* bf = hd==0 ? b_fx : (hd==1 ? b_fy : (hd==2 ? b_fw : b_fh));
  const float* XO = ws + OFF_XO;
  float2 binit = *(const float2*)&bf[kbase + tx*2];
  float acc[4][2];
  #pragma unroll
  for (int i = 0; i < 4; i++) { acc[i][0] = binit.x; acc[i][1] = binit.y; }
  for (int kt = 0; kt < 8; kt++) {
    int k0 = kt*64;
    __syncthreads();
    { // stage A
      int r = tid & 15, q = tid >> 4;
      float4 v = *(const float4*)&XO[(r0+r)*HH + k0 + q*4];
      A_smT[q*4+0][r] = v.x; A_smT[q*4+1][r] = v.y;
      A_smT[q*4+2][r] = v.z; A_smT[q*4+3][r] = v.w;
    }
    for (int p = 0; p < 8; p++) {  // stage W
      int idx = tid + p*256;
      int wc = idx >> 4, kq = idx & 15;
      float4 v = *(const float4*)&Wf[(kbase+wc)*HH + k0 + kq*4];
      w_sm[kq*4+0][wc] = v.x; w_sm[kq*4+1][wc] = v.y;
      w_sm[kq*4+2][wc] = v.z; w_sm[kq*4+3][wc] = v.w;
    }
    __syncthreads();
    #pragma unroll 4
    for (int kk = 0; kk < 64; kk++) {
      float2 w = *(const float2*)&w_sm[kk][tx*2];
      float4 a = *(const float4*)&A_smT[kk][ty*4];
      acc[0][0] = fmaf(a.x, w.x, acc[0][0]); acc[0][1] = fmaf(a.x, w.y, acc[0][1]);
      acc[1][0] = fmaf(a.y, w.x, acc[1][0]); acc[1][1] = fmaf(a.y, w.y, acc[1][1]);
      acc[2][0] = fmaf(a.z, w.x, acc[2][0]); acc[2][1] = fmaf(a.z, w.y, acc[2][1]);
      acc[3][0] = fmaf(a.w, w.x, acc[3][0]); acc[3][1] = fmaf(a.w, w.y, acc[3][1]);
    }
  }
  int ko = kbase + tx*2;
  float* obase = out + (size_t)BB*TT*4 + (size_t)hd*BB*63*KKC;
  unsigned long long* slots = (unsigned long long*)(ws + OFF_SLOT);
  #pragma unroll
  for (int i = 0; i < 4; i++) {
    int b = r0 + ty*4 + i;
    *(float2*)&obase[(size_t)b*63*KKC + (size_t)t*KKC + ko] = make_float2(acc[i][0], acc[i][1]);
    // packed (value, first-index) argmax candidate
    unsigned u0 = encf(acc[i][0]), u1 = encf(acc[i][1]);
    unsigned long long cd;
    if (u1 > u0) cd = ((unsigned long long)u1 << 32) | (unsigned long long)(0xFFFFFFFFu - (unsigned)(ko + 1));
    else         cd = ((unsigned long long)u0 << 32) | (unsigned long long)(0xFFFFFFFFu - (unsigned)ko);
    #pragma unroll
    for (int m = 1; m < 64; m <<= 1) {
      unsigned long long o = shfl_xor_u64(cd, m);
      cd = (o > cd) ? o : cd;
    }
    if (tx == 0) atomicMax(&slots[b*4 + hd], cd);
  }
}

extern "C" void kernel_launch(void* const* d_in, const int* in_sizes, int n_in,
                              void* d_out, int out_size, void* d_ws, size_t ws_size,
                              hipStream_t stream)
{
  const float* obs    = (const float*)d_in[0];
  const float* social = (const float*)d_in[1];
  const int*   maskp  = (const int*)d_in[2];
  const float* cx = (const float*)d_in[3];
  const float* cy = (const float*)d_in[4];
  const float* cw = (const float*)d_in[5];
  const float* ch = (const float*)d_in[6];
  const float* W_rb1 = (const float*)d_in[7];
  const float* b_rb1 = (const float*)d_in[8];
  const float* W_rb2 = (const float*)d_in[9];
  const float* b_rb2 = (const float*)d_in[10];
  const float* W_rbs = (const float*)d_in[11];
  const float* b_rbs = (const float*)d_in[12];
  const float* W_emb = (const float*)d_in[13];
  const float* b_emb = (const float*)d_in[14];
  const float* W_ih  = (const float*)d_in[15];
  const float* b_ih  = (const float*)d_in[16];
  const float* W_hh  = (const float*)d_in[17];
  const float* b_hh  = (const float*)d_in[18];
  const float* W_fx  = (const float*)d_in[19];
  const float* b_fx  = (const float*)d_in[20];
  const float* W_fy  = (const float*)d_in[21];
  const float* b_fy  = (const float*)d_in[22];
  const float* W_fw  = (const float*)d_in[23];
  const float* b_fw  = (const float*)d_in[24];
  const float* W_fh  = (const float*)d_in[25];
  const float* b_fh  = (const float*)d_in[26];
  const float* h0 = (const float*)d_in[27];
  const float* c0 = (const float*)d_in[28];
  float* ws = (float*)d_ws;
  float* out = (float*)d_out;

  hipLaunchKernelGGL(k_init, dim3(512), dim3(256), 0, stream, obs, h0, c0, ws, out);

  for (int t = 0; t < 63; t++) {
    const float* h_cur = ws + ((t & 1) ? OFF_HB : OFF_HA);
    float*       h_nxt = ws + ((t & 1) ? OFF_HA : OFF_HB);
    hipLaunchKernelGGL(k_xe, dim3(256), dim3(256), 0, stream,
                       obs, cx, cy, cw, ch, maskp,
                       W_rb1, b_rb1, W_rb2, b_rb2, W_rbs, b_rbs, ws, out, t);
    hipLaunchKernelGGL(k_xs, dim3(256), dim3(256), 0, stream, social, W_emb, b_emb, ws, t);
    hipLaunchKernelGGL(k_gates, dim3(256), dim3(512), 0, stream,
                       W_ih, b_ih, W_hh, b_hh, ws, h_cur, h_nxt);
    hipLaunchKernelGGL(k_heads, dim3(512), dim3(256), 0, stream,
                       W_fx, b_fx, W_fy, b_fy, W_fw, b_fw, W_fh, b_fh, ws, out, t);
  }
}

// Round 13
// 8130.759 us; speedup vs baseline: 3.4001x; 1.2409x over previous
//
#include <hip/hip_runtime.h>
#include <hip/hip_bf16.h>
#include <hip/hip_fp16.h>
#include <math.h>

// Problem sizes
#define BB 256
#define TT 64
#define HH 512
#define SS 256
#define KKC 1024

// ws float offsets — 788,480 floats = 3.15 MB
#define OFF_XE 0
#define OFF_XS (OFF_XE + BB*HH)
#define OFF_HA (OFF_XS + BB*HH)
#define OFF_HB (OFF_HA + BB*HH)
#define OFF_C  (OFF_HB + BB*HH)
#define OFF_XO (OFF_C  + BB*HH)
#define OFF_SLOT (OFF_XO + BB*HH)   // 1024 u64 argmax slots

__device__ __forceinline__ unsigned encf(float f) {
  unsigned u = __float_as_uint(f);
  return (u & 0x80000000u) ? ~u : (u | 0x80000000u);
}

__device__ __forceinline__ unsigned long long shfl_xor_u64(unsigned long long v, int m) {
  unsigned lo = (unsigned)v, hi = (unsigned)(v >> 32);
  lo = __shfl_xor(lo, m, 64);
  hi = __shfl_xor(hi, m, 64);
  return ((unsigned long long)hi << 32) | lo;
}

// mask decode (robust; proven on this dataset in round 11)
__device__ __forceinline__ int decode_mask(const int* p) {
  if (p == nullptr) return 32;
  unsigned w0 = (unsigned)p[0];
  if (w0 >= 1u && w0 <= 63u) return (int)w0;
  { float f = __uint_as_float(w0);
    if (f >= 1.f && f <= 63.f && f == floorf(f)) return (int)f; }
  if (w0 == 0u) {
    double dv = __hiloint2double(p[1], 0);
    if (dv >= 1.0 && dv <= 63.0 && dv == floor(dv)) return (int)dv;
    return 32;
  }
  if (w0 <= 0xFFFFu) {
    float fb = __uint_as_float(w0 << 16);
    if (fb >= 1.f && fb <= 63.f && fb == floorf(fb)) return (int)fb;
    __half_raw hr; hr.x = (unsigned short)w0;
    float fh = __half2float(__half(hr));
    if (fh >= 1.f && fh <= 63.f && fh == floorf(fh)) return (int)fh;
  }
  return 32;
}

// ---------------- init: h,c and output edges ----------------
__global__ __launch_bounds__(256) void k_init(
    const float* __restrict__ obs, const float* __restrict__ h0,
    const float* __restrict__ c0, float* __restrict__ ws,
    float* __restrict__ out)
{
  int i = blockIdx.x*256 + threadIdx.x;   // 512 blocks -> BB*HH
  ws[OFF_HA + i] = h0[i];
  ws[OFF_C  + i] = c0[i];
  if (i < BB*4) {
    int b = i >> 2, d = i & 3;
    out[(b*TT + 0)*4 + d]  = obs[(b*TT + 0)*4 + d];
    out[(b*TT + 63)*4 + d] = obs[(b*TT + 63)*4 + d];
  }
}

// ---------------- phase 1: sample (fused) + residual block -> xe ----------------
// grid 512 = 32 rowg x 16 colg ; tile 8 rows x 32 cols, k=512 in 8 tiles of 64
__global__ __launch_bounds__(256) void k_xe(
    const float* __restrict__ obs, const float* __restrict__ cx, const float* __restrict__ cy,
    const float* __restrict__ cw, const float* __restrict__ ch, const int* maskp,
    const float* __restrict__ W_rb1, const float* __restrict__ b_rb1,
    const float* __restrict__ W_rb2, const float* __restrict__ b_rb2,
    const float* __restrict__ W_rbs, const float* __restrict__ b_rbs,
    float* __restrict__ ws, float* __restrict__ out, int t)
{
  int bid = blockIdx.x, tid = threadIdx.x;
  int rowg = bid >> 4, colg = bid & 15;
  int r0 = rowg*8, c0 = colg*32;
  __shared__ float x_sm[8][4];
  __shared__ float xr_smT[HH][8];    // 16 KB, transposed fc1 output
  __shared__ float w_sm[64][36];
  if (tid < 32) {
    int r = tid >> 2, hd = tid & 3, b = r0 + r;
    int mi = decode_mask(maskp);
    float v;
    if (t == 0 || t < mi) {
      v = obs[(b*TT + t)*4 + hd];
    } else {
      const unsigned long long* slots = (const unsigned long long*)(ws + OFF_SLOT);
      unsigned long long s = slots[b*4 + hd];
      unsigned int kidx = 0xFFFFFFFFu - (unsigned int)(s & 0xFFFFFFFFull);
      const float* cen = hd==0 ? cx : (hd==1 ? cy : (hd==2 ? cw : ch));
      v = cen[kidx & (KKC-1)];
    }
    x_sm[r][hd] = v;
    if (t >= 1 && colg == 0) out[(b*TT + t)*4 + hd] = v;
  }
  __syncthreads();
  // fc1 + relu (recomputed per block; 8x512 from 4 inputs)
  for (int p = tid; p < 8*HH; p += 256) {
    int r = p & 7, j = p >> 3;
    float4 w = *(const float4*)&W_rb1[j*4];
    float a = b_rb1[j] + x_sm[r][0]*w.x + x_sm[r][1]*w.y + x_sm[r][2]*w.z + x_sm[r][3]*w.w;
    xr_smT[j][r] = fmaxf(a, 0.f);
  }
  int c = tid & 31, rg = tid >> 5;   // 32 cols x 8 rows -> 1 output/thread
  int col = c0 + c;
  float4 wsd = *(const float4*)&W_rbs[col*4];
  float acc = b_rb2[col] + b_rbs[col]
            + x_sm[rg][0]*wsd.x + x_sm[rg][1]*wsd.y
            + x_sm[rg][2]*wsd.z + x_sm[rg][3]*wsd.w;
  for (int kt = 0; kt < 8; kt++) {
    __syncthreads();   // first iter: xr_smT complete; later: prev compute done
    for (int p = 0; p < 2; p++) {
      int idx = tid + p*256;
      int wc = idx >> 4, kq = idx & 15;
      float4 v = *(const float4*)&W_rb2[(c0+wc)*HH + kt*64 + kq*4];
      w_sm[kq*4+0][wc] = v.x; w_sm[kq*4+1][wc] = v.y;
      w_sm[kq*4+2][wc] = v.z; w_sm[kq*4+3][wc] = v.w;
    }
    __syncthreads();
    #pragma unroll 8
    for (int kk = 0; kk < 64; kk++) {
      acc = fmaf(xr_smT[kt*64+kk][rg], w_sm[kk][c], acc);
    }
  }
  ws[OFF_XE + (r0+rg)*HH + col] = fmaxf(acc, 0.f);
}

// ---------------- phase 2: embedding -> xs ----------------
// grid 512 = 32 rowg x 16 colg ; tile 8 x 32, k=768 in 12 tiles of 64
__global__ __launch_bounds__(256) void k_xs(
    const float* __restrict__ social, const float* __restrict__ W_emb,
    const float* __restrict__ b_emb, float* __restrict__ ws, int t)
{
  int bid = blockIdx.x, tid = threadIdx.x;
  int rowg = bid >> 4, colg = bid & 15;
  int r0 = rowg*8, c0 = colg*32;
  __shared__ float A_smT[64][12];
  __shared__ float w_sm[64][36];
  int c = tid & 31, rg = tid >> 5;
  int col = c0 + c;
  float acc = b_emb[col];
  const float* XE = ws + OFF_XE;
  for (int kt = 0; kt < 12; kt++) {
    int k0 = kt*64;
    __syncthreads();
    if (tid < 128) { // stage A tile (transposed): 64k x 8r
      int r = tid & 7, q = tid >> 3;
      const float* src = (kt < 8) ? &XE[(r0+r)*HH + k0 + q*4]
                                  : &social[((size_t)(r0+r)*TT + t)*SS + (k0 - HH) + q*4];
      float4 v = *(const float4*)src;
      A_smT[q*4+0][r] = v.x; A_smT[q*4+1][r] = v.y;
      A_smT[q*4+2][r] = v.z; A_smT[q*4+3][r] = v.w;
    }
    for (int p = 0; p < 2; p++) {  // stage W tile (transposed): 64k x 32col
      int idx = tid + p*256;
      int wc = idx >> 4, kq = idx & 15;
      float4 v = *(const float4*)&W_emb[(c0+wc)*768 + k0 + kq*4];
      w_sm[kq*4+0][wc] = v.x; w_sm[kq*4+1][wc] = v.y;
      w_sm[kq*4+2][wc] = v.z; w_sm[kq*4+3][wc] = v.w;
    }
    __syncthreads();
    #pragma unroll 8
    for (int kk = 0; kk < 64; kk++) {
      acc = fmaf(A_smT[kk][rg], w_sm[kk][c], acc);
    }
  }
  ws[OFF_XS + (r0+rg)*HH + col] = fmaxf(acc, 0.f);
}

// ---------------- phase 3: LSTM gates + cell update ----------------
// grid 512 = 16 rowg x 32 colg ; 256 thr; tile 16 rows x 64 gate-cols, k=1024
// local col l = jl*4 + g  <->  weight row = g*512 + colg*16 + jl
__global__ __launch_bounds__(256) void k_gates(
    const float* __restrict__ W_ih, const float* __restrict__ b_ih,
    const float* __restrict__ W_hh, const float* __restrict__ b_hh,
    float* __restrict__ ws, const float* __restrict__ h_cur,
    float* __restrict__ h_nxt)
{
  int bid = blockIdx.x, tid = threadIdx.x;
  int rowg = bid >> 5, colg = bid & 31;
  int r0 = rowg*16;
  int tx = tid & 63, ty = tid >> 6;   // tx = local col; ty -> rows ty*4..ty*4+3
  __shared__ float A_smT[64][20];
  __shared__ float w_sm[64][66];
  __shared__ float gt[16][66];
  const float* XS = ws + OFF_XS;
  int wrow = (tx & 3)*HH + colg*16 + (tx >> 2);
  float bias = b_ih[wrow] + b_hh[wrow];
  float acc[4];
  #pragma unroll
  for (int i = 0; i < 4; i++) acc[i] = bias;
  for (int kt = 0; kt < 16; kt++) {
    int k0 = kt*64;
    __syncthreads();
    { // stage A: 64k x 16r (256 float4)
      int r = tid & 15, q = tid >> 4;
      const float* src = (kt < 8) ? &XS[(r0+r)*HH + k0 + q*4]
                                  : &h_cur[(r0+r)*HH + (k0 - HH) + q*4];
      float4 v = *(const float4*)src;
      A_smT[q*4+0][r] = v.x; A_smT[q*4+1][r] = v.y;
      A_smT[q*4+2][r] = v.z; A_smT[q*4+3][r] = v.w;
    }
    for (int p = 0; p < 4; p++) {  // stage W: 64k x 64col (1024 float4)
      int idx = tid + p*256;
      int wc = idx >> 4, kq = idx & 15;
      int wr = (wc & 3)*HH + colg*16 + (wc >> 2);
      const float* wsrc = (kt < 8) ? &W_ih[wr*HH + k0 + kq*4]
                                   : &W_hh[wr*HH + (k0 - HH) + kq*4];
      float4 v = *(const float4*)wsrc;
      w_sm[kq*4+0][wc] = v.x; w_sm[kq*4+1][wc] = v.y;
      w_sm[kq*4+2][wc] = v.z; w_sm[kq*4+3][wc] = v.w;
    }
    __syncthreads();
    #pragma unroll 4
    for (int kk = 0; kk < 64; kk++) {
      float w = w_sm[kk][tx];
      float4 a = *(const float4*)&A_smT[kk][ty*4];
      acc[0] = fmaf(a.x, w, acc[0]);
      acc[1] = fmaf(a.y, w, acc[1]);
      acc[2] = fmaf(a.z, w, acc[2]);
      acc[3] = fmaf(a.w, w, acc[3]);
    }
  }
  __syncthreads();
  #pragma unroll
  for (int i = 0; i < 4; i++) gt[ty*4 + i][tx] = acc[i];
  __syncthreads();
  float* C = ws + OFF_C;
  const float* XEb = ws + OFF_XE;
  float* XO = ws + OFF_XO;
  {
    int r = tid >> 4, jl = tid & 15;   // 16 rows x 16 h-units
    float4 g4 = *(const float4*)&gt[r][jl*4];   // i,f,g,o
    int b = r0 + r, jglob = colg*16 + jl;
    float co = C[b*HH + jglob];
    double si = 1.0/(1.0 + exp(-(double)g4.x));
    double sf = 1.0/(1.0 + exp(-(double)g4.y));
    double tg = tanh((double)g4.z);
    double so = 1.0/(1.0 + exp(-(double)g4.w));
    float c2 = (float)(sf*(double)co + si*tg);
    float h2 = (float)(so*tanh((double)c2));
    C[b*HH + jglob] = c2;
    h_nxt[b*HH + jglob] = h2;
    XO[b*HH + jglob] = h2 + XEb[b*HH + jglob];
  }
  // zero argmax slots (after k_xe consumed last step's, before k_heads refills)
  if (bid == 0) {
    unsigned long long* slots = (unsigned long long*)(ws + OFF_SLOT);
    for (int p = tid; p < BB*4; p += 256) slots[p] = 0ull;
  }
}

// ---------------- phase 4: cluster heads (f32) + fused argmax ----------------
// grid 1024 = 16 rowg x 64 colg ; tile 16 rows x 64 head-cols, k=512
__global__ __launch_bounds__(256) void k_heads(
    const float* __restrict__ W_fx, const float* __restrict__ b_fx,
    const float* __restrict__ W_fy, const float* __restrict__ b_fy,
    const float* __restrict__ W_fw, const float* __restrict__ b_fw,
    const float* __restrict__ W_fh, const float* __restrict__ b_fh,
    float* __restrict__ ws, float* __restrict__ out, int t)
{
  int bid = blockIdx.x, tid = threadIdx.x;
  int rowg = bid >> 6, colg = bid & 63;
  int r0 = rowg*16;
  int hd = colg >> 4;
  int kbase = (colg & 15)*64;
  int tx = tid & 63, ty = tid >> 6;
  __shared__ float A_smT[64][20];
  __shared__ float w_sm[64][66];
  const float* Wf = hd==0 ? W_fx : (hd==1 ? W_fy : (hd==2 ? W_fw : W_fh));
  const float* bf = hd==0 ? b_fx : (hd==1 ? b_fy : (hd==2 ? b_fw : b_fh));
  const float* XO = ws + OFF_XO;
  int ko = kbase + tx;
  float binit = bf[ko];
  float acc[4];
  #pragma unroll
  for (int i = 0; i < 4; i++) acc[i] = binit;
  for (int kt = 0; kt < 8; kt++) {
    int k0 = kt*64;
    __syncthreads();
    { // stage A
      int r = tid & 15, q = tid >> 4;
      float4 v = *(const float4*)&XO[(r0+r)*HH + k0 + q*4];
      A_smT[q*4+0][r] = v.x; A_smT[q*4+1][r] = v.y;
      A_smT[q*4+2][r] = v.z; A_smT[q*4+3][r] = v.w;
    }
    for (int p = 0; p < 4; p++) {  // stage W
      int idx = tid + p*256;
      int wc = idx >> 4, kq = idx & 15;
      float4 v = *(const float4*)&Wf[(kbase+wc)*HH + k0 + kq*4];
      w_sm[kq*4+0][wc] = v.x; w_sm[kq*4+1][wc] = v.y;
      w_sm[kq*4+2][wc] = v.z; w_sm[kq*4+3][wc] = v.w;
    }
    __syncthreads();
    #pragma unroll 4
    for (int kk = 0; kk < 64; kk++) {
      float w = w_sm[kk][tx];
      float4 a = *(const float4*)&A_smT[kk][ty*4];
      acc[0] = fmaf(a.x, w, acc[0]);
      acc[1] = fmaf(a.y, w, acc[1]);
      acc[2] = fmaf(a.z, w, acc[2]);
      acc[3] = fmaf(a.w, w, acc[3]);
    }
  }
  float* obase = out + (size_t)BB*TT*4 + (size_t)hd*BB*63*KKC;
  unsigned long long* slots = (unsigned long long*)(ws + OFF_SLOT);
  #pragma unroll
  for (int i = 0; i < 4; i++) {
    int b = r0 + ty*4 + i;
    obase[(size_t)b*63*KKC + (size_t)t*KKC + ko] = acc[i];
    unsigned long long cd = ((unsigned long long)encf(acc[i]) << 32)
                          | (unsigned long long)(0xFFFFFFFFu - (unsigned)ko);
    #pragma unroll
    for (int m = 1; m < 64; m <<= 1) {
      unsigned long long o = shfl_xor_u64(cd, m);
      cd = (o > cd) ? o : cd;
    }
    if (tx == 0) atomicMax(&slots[b*4 + hd], cd);
  }
}

extern "C" void kernel_launch(void* const* d_in, const int* in_sizes, int n_in,
                              void* d_out, int out_size, void* d_ws, size_t ws_size,
                              hipStream_t stream)
{
  const float* obs    = (const float*)d_in[0];
  const float* social = (const float*)d_in[1];
  const int*   maskp  = (const int*)d_in[2];
  const float* cx = (const float*)d_in[3];
  const float* cy = (const float*)d_in[4];
  const float* cw = (const float*)d_in[5];
  const float* ch = (const float*)d_in[6];
  const float* W_rb1 = (const float*)d_in[7];
  const float* b_rb1 = (const float*)d_in[8];
  const float* W_rb2 = (const float*)d_in[9];
  const float* b_rb2 = (const float*)d_in[10];
  const float* W_rbs = (const float*)d_in[11];
  const float* b_rbs = (const float*)d_in[12];
  const float* W_emb = (const float*)d_in[13];
  const float* b_emb = (const float*)d_in[14];
  const float* W_ih  = (const float*)d_in[15];
  const float* b_ih  = (const float*)d_in[16];
  const float* W_hh  = (const float*)d_in[17];
  const float* b_hh  = (const float*)d_in[18];
  const float* W_fx  = (const float*)d_in[19];
  const float* b_fx  = (const float*)d_in[20];
  const float* W_fy  = (const float*)d_in[21];
  const float* b_fy  = (const float*)d_in[22];
  const float* W_fw  = (const float*)d_in[23];
  const float* b_fw  = (const float*)d_in[24];
  const float* W_fh  = (const float*)d_in[25];
  const float* b_fh  = (const float*)d_in[26];
  const float* h0 = (const float*)d_in[27];
  const float* c0 = (const float*)d_in[28];
  float* ws = (float*)d_ws;
  float* out = (float*)d_out;

  hipLaunchKernelGGL(k_init, dim3(512), dim3(256), 0, stream, obs, h0, c0, ws, out);

  for (int t = 0; t < 63; t++) {
    const float* h_cur = ws + ((t & 1) ? OFF_HB : OFF_HA);
    float*       h_nxt = ws + ((t & 1) ? OFF_HA : OFF_HB);
    hipLaunchKernelGGL(k_xe, dim3(512), dim3(256), 0, stream,
                       obs, cx, cy, cw, ch, maskp,
                       W_rb1, b_rb1, W_rb2, b_rb2, W_rbs, b_rbs, ws, out, t);
    hipLaunchKernelGGL(k_xs, dim3(512), dim3(256), 0, stream, social, W_emb, b_emb, ws, t);
    hipLaunchKernelGGL(k_gates, dim3(512), dim3(256), 0, stream,
                       W_ih, b_ih, W_hh, b_hh, ws, h_cur, h_nxt);
    hipLaunchKernelGGL(k_heads, dim3(1024), dim3(256), 0, stream,
                       W_fx, b_fx, W_fy, b_fy, W_fw, b_fw, W_fh, b_fh, ws, out, t);
  }
}